// Round 13
// baseline (251.584 us; speedup 1.0000x reference)
//
#include <hip/hip_runtime.h>
#include <stdint.h>
#include <stddef.h>

typedef _Float16 f16;
typedef _Float16 f16x2 __attribute__((ext_vector_type(2)));
typedef _Float16 f16x8 __attribute__((ext_vector_type(8)));
typedef float    f32x4 __attribute__((ext_vector_type(4)));

#define VOCAB 32000
#define EMBD  200
#define HID   128
#define NB    64
#define NT    64
#define G4    (4*HID)   // 512 gate width

__device__ __forceinline__ float sigf(float x) {
    return __builtin_amdgcn_rcpf(1.f + __expf(-x));
}
__device__ __forceinline__ float tanhf_(float x) {
    return 1.f - 2.f * __builtin_amdgcn_rcpf(1.f + __expf(2.f * x));
}

// prep: blocks [0,256) = embed_w0 (z0 = emb[tokens]@W0 + b0),
//       blocks [256,640) = pack U0,W1,U1 into f16 pairs
__global__ __launch_bounds__(256) void k_prep(
    const int* __restrict__ tokens, const float* __restrict__ emb,
    const float* __restrict__ W0, const float* __restrict__ b0,
    const float* __restrict__ U0, const float* __restrict__ W1,
    const float* __restrict__ U1,
    float* __restrict__ z0, uint32_t* __restrict__ wp) {
    const int t = threadIdx.x;
    if (blockIdx.x >= 256) {
        int idx = (blockIdx.x - 256) * 256 + t;       // [0, 98304)
        int m = idx >> 15;
        int rem = idx & 32767;
        int p = rem >> 9, j = rem & 511;
        const float* W = (m == 0) ? U0 : (m == 1) ? W1 : U1;
        f16x2 v;
        v[0] = (f16)W[(2 * p) * G4 + j];
        v[1] = (f16)W[(2 * p + 1) * G4 + j];
        ((f16x2*)wp)[idx] = v;
        return;
    }
    __shared__ __align__(16) float xs[EMBD * 16];   // [k][r]
    __shared__ int tok[16];
    const int blk = blockIdx.x;
    if (t < 16) tok[t] = tokens[blk * 16 + t];
    __syncthreads();
    for (int i = t; i < EMBD * 16; i += 256) {
        int r = i / EMBD, k = i - r * EMBD;
        xs[k * 16 + r] = emb[(size_t)tok[r] * EMBD + k];
    }
    __syncthreads();
    const int j = t * 2;
    f32x4 accA[4], accB[4];
#pragma unroll
    for (int grp = 0; grp < 4; ++grp) {
        accA[grp] = f32x4{0.f, 0.f, 0.f, 0.f};
        accB[grp] = f32x4{0.f, 0.f, 0.f, 0.f};
    }
    for (int k = 0; k < EMBD; ++k) {
        float2 w = *(const float2*)(W0 + (size_t)k * G4 + j);
        const f32x4* xv = (const f32x4*)(xs + k * 16);
#pragma unroll
        for (int grp = 0; grp < 4; ++grp) {
            f32x4 x = xv[grp];
            accA[grp] += x * w.x;
            accB[grp] += x * w.y;
        }
    }
    float bx = b0[j], by = b0[j + 1];
#pragma unroll
    for (int grp = 0; grp < 4; ++grp)
#pragma unroll
        for (int r = 0; r < 4; ++r) {
            int row = blk * 16 + grp * 4 + r;
            float2 o; o.x = accA[grp][r] + bx; o.y = accB[grp][r] + by;
            *(float2*)(z0 + (size_t)row * G4 + j) = o;
        }
}

// scan: blocks [0,64) = LSTM scan (2 barriers/step, merged dot phase, gates
// pipelined one step ahead). blocks [64,564) = Wout transpose (if do_wt).
// H1 layout batch-major: H1[b][t][128].
__global__ __launch_bounds__(512, 1) void k_scan(
    const float* __restrict__ z0base, const uint32_t* __restrict__ wp,
    const float* __restrict__ b1, f16* __restrict__ H1,
    const float* __restrict__ Wout, f16* __restrict__ WoutT,
    int role_ofs, int do_wt) {
    __shared__ __align__(16) char smem[17408];
    const int bid = blockIdx.x + role_ofs;
    const int t = threadIdx.x;

    if (bid >= 64) {
        if (!do_wt) return;
        // ---- transpose Wout f32 [128][32000] -> WoutT f16 [32000][128] ----
        f16* tile = (f16*)smem;                 // [64][136]
        const int n0 = (bid - 64) * 64;
        for (int i = t; i < 64 * 128; i += 512) {
            int k = i >> 6, n = i & 63;
            tile[n * 136 + k] = (f16)Wout[(size_t)k * VOCAB + n0 + n];
        }
        __syncthreads();
        for (int i = t; i < 1024; i += 512) {
            int n = i >> 4, u = i & 15;
            *(uint4*)(WoutT + (size_t)(n0 + n) * HID + u * 8) =
                *(const uint4*)&tile[n * 136 + u * 8];
        }
        return;
    }

    // ================= scan =================
    const int b = bid;
    const int g = t >> 7, q = t & 127;
    float* zA = (float*)smem;              // [4][512] layer-0 partials
    float* zC = (float*)(smem + 8192);     // [4][512] layer-1 partials
    f16* h0s = (f16*)(smem + 16384);
    f16* h1s = (f16*)(smem + 16640);

    const f16x8* wp8 = (const f16x8*)wp;
    f16x2 wu0[64], ww1[64], wu1[64];       // 192 VGPRs of weights
    const int wbase = (g * 16) * 128 + q;
#pragma unroll
    for (int kk = 0; kk < 16; ++kk) {
        *(f16x8*)&wu0[kk * 4] = wp8[0 * 8192 + wbase + kk * 128];
        *(f16x8*)&ww1[kk * 4] = wp8[1 * 8192 + wbase + kk * 128];
        *(f16x8*)&wu1[kk * 4] = wp8[2 * 8192 + wbase + kk * 128];
    }
    float b1a = 0.f, b1b = 0.f, b1c = 0.f, b1d = 0.f;
    float c0 = 0.f, c1 = 0.f;
    if (t < HID) {
        b1a = b1[t]; b1b = b1[t + 128]; b1c = b1[t + 256]; b1d = b1[t + 384];
        // step-0 layer-0 gates: U0 contribution is 0 (h0 init = 0)
        const float* zr = z0base + (size_t)b * NT * G4 + t;
        float zi = zr[0], zg = zr[256], zo = zr[384];
        c0 = sigf(zi) * tanhf_(zg);        // f*c_prev(=0) dropped
        h0s[t] = (f16)(sigf(zo) * tanhf_(c0));
        h1s[t] = (f16)0.f;
    }
    __syncthreads();

    const float* zb = z0base + (size_t)b * NT * G4;
    f16* hout = H1 + (size_t)b * NT * HID;

    for (int s = 0; s < NT; ++s) {
        // prefetch z0 row s+1 (consumed by layer-0 gates of step s+1)
        float za = 0.f, zbv = 0.f, zc = 0.f, zd = 0.f;
        if (t < HID) {
            int nx = (s < 63) ? (s + 1) : 63;
            const float* zr = zb + (size_t)nx * G4 + t;
            za = zr[0]; zbv = zr[128]; zc = zr[256]; zd = zr[384];
        }
        // merged dot phase: zA = U0.h0(s); zC = W1.h0(s) + U1.h1(s-1)
        float aA0 = 0.f, aA1 = 0.f, aA2 = 0.f, aA3 = 0.f;
        float aC0 = 0.f, aC1 = 0.f, aC2 = 0.f, aC3 = 0.f;
        {
            f16x2 hh[16];
            const f16x8* hp0 = (const f16x8*)h0s + g * 4;
            *(f16x8*)&hh[0] = hp0[0]; *(f16x8*)&hh[4] = hp0[1];
            *(f16x8*)&hh[8] = hp0[2]; *(f16x8*)&hh[12] = hp0[3];
#pragma unroll
            for (int kk = 0; kk < 16; ++kk) {
                f16x2 h = hh[kk];
                aA0 = __builtin_amdgcn_fdot2(wu0[kk * 4 + 0], h, aA0, false);
                aA1 = __builtin_amdgcn_fdot2(wu0[kk * 4 + 1], h, aA1, false);
                aA2 = __builtin_amdgcn_fdot2(wu0[kk * 4 + 2], h, aA2, false);
                aA3 = __builtin_amdgcn_fdot2(wu0[kk * 4 + 3], h, aA3, false);
                aC0 = __builtin_amdgcn_fdot2(ww1[kk * 4 + 0], h, aC0, false);
                aC1 = __builtin_amdgcn_fdot2(ww1[kk * 4 + 1], h, aC1, false);
                aC2 = __builtin_amdgcn_fdot2(ww1[kk * 4 + 2], h, aC2, false);
                aC3 = __builtin_amdgcn_fdot2(ww1[kk * 4 + 3], h, aC3, false);
            }
            const f16x8* hp1 = (const f16x8*)h1s + g * 4;
            *(f16x8*)&hh[0] = hp1[0]; *(f16x8*)&hh[4] = hp1[1];
            *(f16x8*)&hh[8] = hp1[2]; *(f16x8*)&hh[12] = hp1[3];
#pragma unroll
            for (int kk = 0; kk < 16; ++kk) {
                f16x2 h = hh[kk];
                aC0 = __builtin_amdgcn_fdot2(wu1[kk * 4 + 0], h, aC0, false);
                aC1 = __builtin_amdgcn_fdot2(wu1[kk * 4 + 1], h, aC1, false);
                aC2 = __builtin_amdgcn_fdot2(wu1[kk * 4 + 2], h, aC2, false);
                aC3 = __builtin_amdgcn_fdot2(wu1[kk * 4 + 3], h, aC3, false);
            }
        }
        *(f32x4*)&zA[g * 512 + (q << 2)] = f32x4{aA0, aA1, aA2, aA3};
        *(f32x4*)&zC[g * 512 + (q << 2)] = f32x4{aC0, aC1, aC2, aC3};
        __syncthreads();                                       // 1
        if (t < HID) {
            // layer-1 gates, step s
            float z1i = b1a + zC[t]        + zC[512 + t]        + zC[1024 + t]        + zC[1536 + t];
            float z1f = b1b + zC[t + 128]  + zC[512 + t + 128]  + zC[1024 + t + 128]  + zC[1536 + t + 128];
            float z1g = b1c + zC[t + 256]  + zC[512 + t + 256]  + zC[1024 + t + 256]  + zC[1536 + t + 256];
            float z1o = b1d + zC[t + 384]  + zC[512 + t + 384]  + zC[1024 + t + 384]  + zC[1536 + t + 384];
            c1 = sigf(z1f) * c1 + sigf(z1i) * tanhf_(z1g);
            float h1v = sigf(z1o) * tanhf_(c1);
            f16 hf = (f16)h1v;
            h1s[t] = hf;
            hout[s * HID + t] = hf;
            // layer-0 gates, step s+1
            if (s < 63) {
                float z0i = za  + zA[t]       + zA[512 + t]       + zA[1024 + t]       + zA[1536 + t];
                float z0f = zbv + zA[t + 128] + zA[512 + t + 128] + zA[1024 + t + 128] + zA[1536 + t + 128];
                float z0g = zc  + zA[t + 256] + zA[512 + t + 256] + zA[1024 + t + 256] + zA[1536 + t + 256];
                float z0o = zd  + zA[t + 384] + zA[512 + t + 384] + zA[1024 + t + 384] + zA[1536 + t + 384];
                c0 = sigf(z0f) * c0 + sigf(z0i) * tanhf_(z0g);
                h0s[t] = (f16)(sigf(z0o) * tanhf_(c0));
            }
        }
        __syncthreads();                                       // 2
    }
}

// k_gemm8: R12 structure, 256-col slabs (quarters A-refetch to 125MB).
// Grid = 125 n-slabs x 8 m-eighths (512 rows, 8 x 64-row iters) = 1000 blocks.
// Wave w owns cols [n0+64w, +64) as 4 col-groups (wfrag 64 VGPRs);
// 64-row A tiles double-buffered in 2x16KB LDS; 1 barrier/iter.
__global__ __launch_bounds__(256) void k_gemm8(
    const f16* __restrict__ H1, const f16* __restrict__ WT,
    const float* __restrict__ bout, float* __restrict__ out) {
    __shared__ __align__(16) f16 Asub[2][64 * 128];   // 2 x 16KB
    const int t = threadIdx.x;
    const int w = t >> 6, l = t & 63;
    const int lr = l & 15, lk = l >> 4;
    const int slab = blockIdx.x % 125;     // 256-wide n-slab
    const int me   = blockIdx.x / 125;     // m-eighth (512 rows)
    const int n0 = slab * 256;
    const int mbase = me * 512;

    // B (Wout) fragments: wave w, col-group s covers n-rows [n0+64w+16s, +16)
    f16x8 wfrag[4][4];
#pragma unroll
    for (int s = 0; s < 4; ++s)
#pragma unroll
        for (int ks = 0; ks < 4; ++ks)
            wfrag[s][ks] = *(const f16x8*)&WT[
                (size_t)(n0 + w * 64 + s * 16 + lr) * HID + ks * 32 + lk * 8];
    float4 bv[4];
#pragma unroll
    for (int s = 0; s < 4; ++s)
        bv[s] = *(const float4*)&bout[n0 + w * 64 + s * 16 + lk * 4];

    // prologue: stage tile 0 (64 rows; 4 uint4 per thread, XOR granule swizzle)
    {
        const uint4* Ag = (const uint4*)(H1 + (size_t)mbase * HID);
#pragma unroll
        for (int i = 0; i < 4; ++i) {
            int Gr = i * 256 + t;
            int row = Gr >> 4, gg = Gr & 15;
            ((uint4*)Asub[0])[(row << 4) | (gg ^ (row & 7))] = Ag[Gr];
        }
    }
    __syncthreads();

    for (int it = 0; it < 8; ++it) {
        const int cur = it & 1;
        if (it < 7) {
            const uint4* Ag = (const uint4*)(H1 + (size_t)(mbase + (it + 1) * 64) * HID);
#pragma unroll
            for (int i = 0; i < 4; ++i) {
                int Gr = i * 256 + t;
                int row = Gr >> 4, gg = Gr & 15;
                ((uint4*)Asub[cur ^ 1])[(row << 4) | (gg ^ (row & 7))] = Ag[Gr];
            }
        }
        const f16* Ab = Asub[cur];
        const int mb = mbase + it * 64;
#pragma unroll
        for (int mt = 0; mt < 4; ++mt) {
            const int row = mt * 16 + lr;
            f16x8 af[4];
#pragma unroll
            for (int ks = 0; ks < 4; ++ks)
                af[ks] = *(const f16x8*)&Ab[(row << 7) + (((ks * 4 + lk) ^ (row & 7)) << 3)];
            const size_t orow = (size_t)(mb + mt * 16 + lr) * VOCAB;
#pragma unroll
            for (int s = 0; s < 4; ++s) {
                f32x4 acc = f32x4{0.f, 0.f, 0.f, 0.f};
                acc = __builtin_amdgcn_mfma_f32_16x16x32_f16(wfrag[s][0], af[0], acc, 0, 0, 0);
                acc = __builtin_amdgcn_mfma_f32_16x16x32_f16(wfrag[s][1], af[1], acc, 0, 0, 0);
                acc = __builtin_amdgcn_mfma_f32_16x16x32_f16(wfrag[s][2], af[2], acc, 0, 0, 0);
                acc = __builtin_amdgcn_mfma_f32_16x16x32_f16(wfrag[s][3], af[3], acc, 0, 0, 0);
                float4 o;
                o.x = acc[0] + bv[s].x; o.y = acc[1] + bv[s].y;
                o.z = acc[2] + bv[s].z; o.w = acc[3] + bv[s].w;
                o.x = o.x > 0.f ? o.x : 0.f;
                o.y = o.y > 0.f ? o.y : 0.f;
                o.z = o.z > 0.f ? o.z : 0.f;
                o.w = o.w > 0.f ? o.w : 0.f;
                *(float4*)&out[orow + n0 + w * 64 + s * 16 + lk * 4] = o;
            }
        }
        __syncthreads();
    }
}

extern "C" void kernel_launch(void* const* d_in, const int* in_sizes, int n_in,
                              void* d_out, int out_size, void* d_ws, size_t ws_size,
                              hipStream_t stream) {
    const int*   tokens = (const int*)d_in[0];
    const float* emb  = (const float*)d_in[1];
    const float* W0   = (const float*)d_in[2];
    const float* U0   = (const float*)d_in[3];
    const float* b0   = (const float*)d_in[4];
    const float* W1   = (const float*)d_in[5];
    const float* U1   = (const float*)d_in[6];
    const float* b1   = (const float*)d_in[7];
    const float* Wout = (const float*)d_in[8];
    const float* bout = (const float*)d_in[9];
    float* out = (float*)d_out;

    // ws: z0base f32 @0 (8,388,608) | wp @8,388,608 (393,216)
    //     H1 @8,781,824 (1,048,576) | WoutT @9,834,496 (8,192,000) if ws allows,
    //     else WoutT aliases z0base (transpose runs after the scan).
    char* ws = (char*)d_ws;
    float*    z0base = (float*)ws;
    uint32_t* wp     = (uint32_t*)(ws + 8388608);
    f16*      H1     = (f16*)(ws + 8781824);
    const bool big_ws = ws_size >= (size_t)18026496;
    f16*      WoutT  = big_ws ? (f16*)(ws + 9834496) : (f16*)ws;

    k_prep<<<640, 256, 0, stream>>>(tokens, emb, W0, b0, U0, W1, U1, z0base, wp);
    // scan + (if big_ws) Wout transpose riding on idle CUs
    k_scan<<<564, 512, 0, stream>>>(z0base, wp, b1, H1, Wout, WoutT, 0,
                                    big_ws ? 1 : 0);
    if (!big_ws)  // small-ws: transpose after scan (WoutT aliases dead z0base)
        k_scan<<<500, 512, 0, stream>>>(z0base, wp, b1, H1, Wout, WoutT, 64, 1);
    k_gemm8<<<1000, 256, 0, stream>>>(H1, WoutT, bout, out);
}

// Round 14
// 242.445 us; speedup vs baseline: 1.0377x; 1.0377x over previous
//
#include <hip/hip_runtime.h>
#include <stdint.h>
#include <stddef.h>

typedef _Float16 f16;
typedef _Float16 f16x2 __attribute__((ext_vector_type(2)));
typedef _Float16 f16x8 __attribute__((ext_vector_type(8)));
typedef float    f32x4 __attribute__((ext_vector_type(4)));

#define VOCAB 32000
#define EMBD  200
#define HID   128
#define NB    64
#define NT    64
#define G4    (4*HID)   // 512 gate width

__device__ __forceinline__ float sigf(float x) {
    return __builtin_amdgcn_rcpf(1.f + __expf(-x));
}
__device__ __forceinline__ float tanhf_(float x) {
    return 1.f - 2.f * __builtin_amdgcn_rcpf(1.f + __expf(2.f * x));
}

// prep: blocks [0,256) = embed_w0 (z0 = emb[tokens]@W0 + b0),
//       blocks [256,640) = pack U0,W1,U1 into f16 pairs
__global__ __launch_bounds__(256) void k_prep(
    const int* __restrict__ tokens, const float* __restrict__ emb,
    const float* __restrict__ W0, const float* __restrict__ b0,
    const float* __restrict__ U0, const float* __restrict__ W1,
    const float* __restrict__ U1,
    float* __restrict__ z0, uint32_t* __restrict__ wp) {
    const int t = threadIdx.x;
    if (blockIdx.x >= 256) {
        int idx = (blockIdx.x - 256) * 256 + t;       // [0, 98304)
        int m = idx >> 15;
        int rem = idx & 32767;
        int p = rem >> 9, j = rem & 511;
        const float* W = (m == 0) ? U0 : (m == 1) ? W1 : U1;
        f16x2 v;
        v[0] = (f16)W[(2 * p) * G4 + j];
        v[1] = (f16)W[(2 * p + 1) * G4 + j];
        ((f16x2*)wp)[idx] = v;
        return;
    }
    __shared__ __align__(16) float xs[EMBD * 16];   // [k][r]
    __shared__ int tok[16];
    const int blk = blockIdx.x;
    if (t < 16) tok[t] = tokens[blk * 16 + t];
    __syncthreads();
    for (int i = t; i < EMBD * 16; i += 256) {
        int r = i / EMBD, k = i - r * EMBD;
        xs[k * 16 + r] = emb[(size_t)tok[r] * EMBD + k];
    }
    __syncthreads();
    const int j = t * 2;
    f32x4 accA[4], accB[4];
#pragma unroll
    for (int grp = 0; grp < 4; ++grp) {
        accA[grp] = f32x4{0.f, 0.f, 0.f, 0.f};
        accB[grp] = f32x4{0.f, 0.f, 0.f, 0.f};
    }
    for (int k = 0; k < EMBD; ++k) {
        float2 w = *(const float2*)(W0 + (size_t)k * G4 + j);
        const f32x4* xv = (const f32x4*)(xs + k * 16);
#pragma unroll
        for (int grp = 0; grp < 4; ++grp) {
            f32x4 x = xv[grp];
            accA[grp] += x * w.x;
            accB[grp] += x * w.y;
        }
    }
    float bx = b0[j], by = b0[j + 1];
#pragma unroll
    for (int grp = 0; grp < 4; ++grp)
#pragma unroll
        for (int r = 0; r < 4; ++r) {
            int row = blk * 16 + grp * 4 + r;
            float2 o; o.x = accA[grp][r] + bx; o.y = accB[grp][r] + by;
            *(float2*)(z0 + (size_t)row * G4 + j) = o;
        }
}

// scan: blocks [0,64) = LSTM scan (2 barriers/step, merged dot phase, gates
// pipelined one step ahead). blocks [64,564) = Wout transpose (if do_wt).
// H1 layout batch-major: H1[b][t][128].
__global__ __launch_bounds__(512, 1) void k_scan(
    const float* __restrict__ z0base, const uint32_t* __restrict__ wp,
    const float* __restrict__ b1, f16* __restrict__ H1,
    const float* __restrict__ Wout, f16* __restrict__ WoutT,
    int role_ofs, int do_wt) {
    __shared__ __align__(16) char smem[17408];
    const int bid = blockIdx.x + role_ofs;
    const int t = threadIdx.x;

    if (bid >= 64) {
        if (!do_wt) return;
        // ---- transpose Wout f32 [128][32000] -> WoutT f16 [32000][128] ----
        f16* tile = (f16*)smem;                 // [64][136]
        const int n0 = (bid - 64) * 64;
        for (int i = t; i < 64 * 128; i += 512) {
            int k = i >> 6, n = i & 63;
            tile[n * 136 + k] = (f16)Wout[(size_t)k * VOCAB + n0 + n];
        }
        __syncthreads();
        for (int i = t; i < 1024; i += 512) {
            int n = i >> 4, u = i & 15;
            *(uint4*)(WoutT + (size_t)(n0 + n) * HID + u * 8) =
                *(const uint4*)&tile[n * 136 + u * 8];
        }
        return;
    }

    // ================= scan =================
    const int b = bid;
    const int g = t >> 7, q = t & 127;
    float* zA = (float*)smem;              // [4][512] layer-0 partials
    float* zC = (float*)(smem + 8192);     // [4][512] layer-1 partials
    f16* h0s = (f16*)(smem + 16384);
    f16* h1s = (f16*)(smem + 16640);

    const f16x8* wp8 = (const f16x8*)wp;
    f16x2 wu0[64], ww1[64], wu1[64];       // 192 VGPRs of weights
    const int wbase = (g * 16) * 128 + q;
#pragma unroll
    for (int kk = 0; kk < 16; ++kk) {
        *(f16x8*)&wu0[kk * 4] = wp8[0 * 8192 + wbase + kk * 128];
        *(f16x8*)&ww1[kk * 4] = wp8[1 * 8192 + wbase + kk * 128];
        *(f16x8*)&wu1[kk * 4] = wp8[2 * 8192 + wbase + kk * 128];
    }
    float b1a = 0.f, b1b = 0.f, b1c = 0.f, b1d = 0.f;
    float c0 = 0.f, c1 = 0.f;
    if (t < HID) {
        b1a = b1[t]; b1b = b1[t + 128]; b1c = b1[t + 256]; b1d = b1[t + 384];
        // step-0 layer-0 gates: U0 contribution is 0 (h0 init = 0)
        const float* zr = z0base + (size_t)b * NT * G4 + t;
        float zi = zr[0], zg = zr[256], zo = zr[384];
        c0 = sigf(zi) * tanhf_(zg);        // f*c_prev(=0) dropped
        h0s[t] = (f16)(sigf(zo) * tanhf_(c0));
        h1s[t] = (f16)0.f;
    }
    __syncthreads();

    const float* zb = z0base + (size_t)b * NT * G4;
    f16* hout = H1 + (size_t)b * NT * HID;

    for (int s = 0; s < NT; ++s) {
        // prefetch z0 row s+1 (consumed by layer-0 gates of step s+1)
        float za = 0.f, zbv = 0.f, zc = 0.f, zd = 0.f;
        if (t < HID) {
            int nx = (s < 63) ? (s + 1) : 63;
            const float* zr = zb + (size_t)nx * G4 + t;
            za = zr[0]; zbv = zr[128]; zc = zr[256]; zd = zr[384];
        }
        // merged dot phase: zA = U0.h0(s); zC = W1.h0(s) + U1.h1(s-1)
        float aA0 = 0.f, aA1 = 0.f, aA2 = 0.f, aA3 = 0.f;
        float aC0 = 0.f, aC1 = 0.f, aC2 = 0.f, aC3 = 0.f;
        {
            f16x2 hh[16];
            const f16x8* hp0 = (const f16x8*)h0s + g * 4;
            *(f16x8*)&hh[0] = hp0[0]; *(f16x8*)&hh[4] = hp0[1];
            *(f16x8*)&hh[8] = hp0[2]; *(f16x8*)&hh[12] = hp0[3];
#pragma unroll
            for (int kk = 0; kk < 16; ++kk) {
                f16x2 h = hh[kk];
                aA0 = __builtin_amdgcn_fdot2(wu0[kk * 4 + 0], h, aA0, false);
                aA1 = __builtin_amdgcn_fdot2(wu0[kk * 4 + 1], h, aA1, false);
                aA2 = __builtin_amdgcn_fdot2(wu0[kk * 4 + 2], h, aA2, false);
                aA3 = __builtin_amdgcn_fdot2(wu0[kk * 4 + 3], h, aA3, false);
                aC0 = __builtin_amdgcn_fdot2(ww1[kk * 4 + 0], h, aC0, false);
                aC1 = __builtin_amdgcn_fdot2(ww1[kk * 4 + 1], h, aC1, false);
                aC2 = __builtin_amdgcn_fdot2(ww1[kk * 4 + 2], h, aC2, false);
                aC3 = __builtin_amdgcn_fdot2(ww1[kk * 4 + 3], h, aC3, false);
            }
            const f16x8* hp1 = (const f16x8*)h1s + g * 4;
            *(f16x8*)&hh[0] = hp1[0]; *(f16x8*)&hh[4] = hp1[1];
            *(f16x8*)&hh[8] = hp1[2]; *(f16x8*)&hh[12] = hp1[3];
#pragma unroll
            for (int kk = 0; kk < 16; ++kk) {
                f16x2 h = hh[kk];
                aC0 = __builtin_amdgcn_fdot2(wu1[kk * 4 + 0], h, aC0, false);
                aC1 = __builtin_amdgcn_fdot2(wu1[kk * 4 + 1], h, aC1, false);
                aC2 = __builtin_amdgcn_fdot2(wu1[kk * 4 + 2], h, aC2, false);
                aC3 = __builtin_amdgcn_fdot2(wu1[kk * 4 + 3], h, aC3, false);
            }
        }
        *(f32x4*)&zA[g * 512 + (q << 2)] = f32x4{aA0, aA1, aA2, aA3};
        *(f32x4*)&zC[g * 512 + (q << 2)] = f32x4{aC0, aC1, aC2, aC3};
        __syncthreads();                                       // 1
        if (t < HID) {
            // layer-1 gates, step s
            float z1i = b1a + zC[t]        + zC[512 + t]        + zC[1024 + t]        + zC[1536 + t];
            float z1f = b1b + zC[t + 128]  + zC[512 + t + 128]  + zC[1024 + t + 128]  + zC[1536 + t + 128];
            float z1g = b1c + zC[t + 256]  + zC[512 + t + 256]  + zC[1024 + t + 256]  + zC[1536 + t + 256];
            float z1o = b1d + zC[t + 384]  + zC[512 + t + 384]  + zC[1024 + t + 384]  + zC[1536 + t + 384];
            c1 = sigf(z1f) * c1 + sigf(z1i) * tanhf_(z1g);
            float h1v = sigf(z1o) * tanhf_(c1);
            f16 hf = (f16)h1v;
            h1s[t] = hf;
            hout[s * HID + t] = hf;
            // layer-0 gates, step s+1
            if (s < 63) {
                float z0i = za  + zA[t]       + zA[512 + t]       + zA[1024 + t]       + zA[1536 + t];
                float z0f = zbv + zA[t + 128] + zA[512 + t + 128] + zA[1024 + t + 128] + zA[1536 + t + 128];
                float z0g = zc  + zA[t + 256] + zA[512 + t + 256] + zA[1024 + t + 256] + zA[1536 + t + 256];
                float z0o = zd  + zA[t + 384] + zA[512 + t + 384] + zA[1024 + t + 384] + zA[1536 + t + 384];
                c0 = sigf(z0f) * c0 + sigf(z0i) * tanhf_(z0g);
                h0s[t] = (f16)(sigf(z0o) * tanhf_(c0));
            }
        }
        __syncthreads();                                       // 2
    }
}

// k_gemm7: best measured GEMM (R12). 128-col slabs, 64-row dbuf'd A tiles,
// grid = 250 n-slabs x 4 m-quarters = 1000 blocks (~5/CU, 2x16KB LDS).
// Wave w owns cols [n0+32w, +32) as 2 col-groups; 1 barrier/iter.
__global__ __launch_bounds__(256) void k_gemm7(
    const f16* __restrict__ H1, const f16* __restrict__ WT,
    const float* __restrict__ bout, float* __restrict__ out) {
    __shared__ __align__(16) f16 Asub[2][64 * 128];   // 2 x 16KB
    const int t = threadIdx.x;
    const int w = t >> 6, l = t & 63;
    const int lr = l & 15, lk = l >> 4;
    const int slab = blockIdx.x % 250;     // 128-wide n-slab
    const int mq   = blockIdx.x / 250;     // m-quarter (1024 rows)
    const int n0 = slab * 128;
    const int mbase = mq * 1024;

    // B (Wout) fragments: wave w, col-group s covers n-rows [n0+32w+16s, +16)
    f16x8 wfrag[2][4];
#pragma unroll
    for (int s = 0; s < 2; ++s)
#pragma unroll
        for (int ks = 0; ks < 4; ++ks)
            wfrag[s][ks] = *(const f16x8*)&WT[
                (size_t)(n0 + w * 32 + s * 16 + lr) * HID + ks * 32 + lk * 8];
    float4 bv[2];
#pragma unroll
    for (int s = 0; s < 2; ++s)
        bv[s] = *(const float4*)&bout[n0 + w * 32 + s * 16 + lk * 4];

    // prologue: stage tile 0 (64 rows; 4 uint4 per thread, XOR granule swizzle)
    {
        const uint4* Ag = (const uint4*)(H1 + (size_t)mbase * HID);
#pragma unroll
        for (int i = 0; i < 4; ++i) {
            int Gr = i * 256 + t;
            int row = Gr >> 4, gg = Gr & 15;
            ((uint4*)Asub[0])[(row << 4) | (gg ^ (row & 7))] = Ag[Gr];
        }
    }
    __syncthreads();

    for (int it = 0; it < 16; ++it) {
        const int cur = it & 1;
        if (it < 15) {
            const uint4* Ag = (const uint4*)(H1 + (size_t)(mbase + (it + 1) * 64) * HID);
#pragma unroll
            for (int i = 0; i < 4; ++i) {
                int Gr = i * 256 + t;
                int row = Gr >> 4, gg = Gr & 15;
                ((uint4*)Asub[cur ^ 1])[(row << 4) | (gg ^ (row & 7))] = Ag[Gr];
            }
        }
        const f16* Ab = Asub[cur];
        const int mb = mbase + it * 64;
#pragma unroll
        for (int mt = 0; mt < 4; ++mt) {
            const int row = mt * 16 + lr;
            f16x8 af[4];
#pragma unroll
            for (int ks = 0; ks < 4; ++ks)
                af[ks] = *(const f16x8*)&Ab[(row << 7) + (((ks * 4 + lk) ^ (row & 7)) << 3)];
            const size_t orow = (size_t)(mb + mt * 16 + lr) * VOCAB;
#pragma unroll
            for (int s = 0; s < 2; ++s) {
                f32x4 acc = f32x4{0.f, 0.f, 0.f, 0.f};
                acc = __builtin_amdgcn_mfma_f32_16x16x32_f16(wfrag[s][0], af[0], acc, 0, 0, 0);
                acc = __builtin_amdgcn_mfma_f32_16x16x32_f16(wfrag[s][1], af[1], acc, 0, 0, 0);
                acc = __builtin_amdgcn_mfma_f32_16x16x32_f16(wfrag[s][2], af[2], acc, 0, 0, 0);
                acc = __builtin_amdgcn_mfma_f32_16x16x32_f16(wfrag[s][3], af[3], acc, 0, 0, 0);
                float4 o;
                o.x = acc[0] + bv[s].x; o.y = acc[1] + bv[s].y;
                o.z = acc[2] + bv[s].z; o.w = acc[3] + bv[s].w;
                o.x = o.x > 0.f ? o.x : 0.f;
                o.y = o.y > 0.f ? o.y : 0.f;
                o.z = o.z > 0.f ? o.z : 0.f;
                o.w = o.w > 0.f ? o.w : 0.f;
                *(float4*)&out[orow + n0 + w * 32 + s * 16 + lk * 4] = o;
            }
        }
        __syncthreads();
    }
}

extern "C" void kernel_launch(void* const* d_in, const int* in_sizes, int n_in,
                              void* d_out, int out_size, void* d_ws, size_t ws_size,
                              hipStream_t stream) {
    const int*   tokens = (const int*)d_in[0];
    const float* emb  = (const float*)d_in[1];
    const float* W0   = (const float*)d_in[2];
    const float* U0   = (const float*)d_in[3];
    const float* b0   = (const float*)d_in[4];
    const float* W1   = (const float*)d_in[5];
    const float* U1   = (const float*)d_in[6];
    const float* b1   = (const float*)d_in[7];
    const float* Wout = (const float*)d_in[8];
    const float* bout = (const float*)d_in[9];
    float* out = (float*)d_out;

    // ws: z0base f32 @0 (8,388,608) | wp @8,388,608 (393,216)
    //     H1 @8,781,824 (1,048,576) | WoutT @9,834,496 (8,192,000) if ws allows,
    //     else WoutT aliases z0base (transpose runs after the scan).
    char* ws = (char*)d_ws;
    float*    z0base = (float*)ws;
    uint32_t* wp     = (uint32_t*)(ws + 8388608);
    f16*      H1     = (f16*)(ws + 8781824);
    const bool big_ws = ws_size >= (size_t)18026496;
    f16*      WoutT  = big_ws ? (f16*)(ws + 9834496) : (f16*)ws;

    k_prep<<<640, 256, 0, stream>>>(tokens, emb, W0, b0, U0, W1, U1, z0base, wp);
    // scan + (if big_ws) Wout transpose riding on idle CUs
    k_scan<<<564, 512, 0, stream>>>(z0base, wp, b1, H1, Wout, WoutT, 0,
                                    big_ws ? 1 : 0);
    if (!big_ws)  // small-ws: transpose after scan (WoutT aliases dead z0base)
        k_scan<<<500, 512, 0, stream>>>(z0base, wp, b1, H1, Wout, WoutT, 64, 1);
    k_gemm7<<<1000, 256, 0, stream>>>(H1, WoutT, bout, out);
}